// Round 4
// baseline (876.377 us; speedup 1.0000x reference)
//
#include <hip/hip_runtime.h>
#include <hip/hip_bf16.h>
#include <cstdint>
#include <cstddef>

// Problem constants
#define B_ 64
#define S_ 4096
#define D_ 256
#define TPB 1024                 // 16 waves
#define NBLK 256                 // 1 block per CU; 256*1024 = 262144 rows
#define ROWS_PER_BLOCK 1024
#define BLKS_PER_BATCH 4         // 4096 rows/batch / 1024 rows/block

typedef __attribute__((ext_vector_type(8))) short short8;
typedef __attribute__((ext_vector_type(4))) float f32x4;
typedef __attribute__((ext_vector_type(4))) float f4;

__device__ __forceinline__ short f2bf(float f) {
  union { float f; uint32_t u; } v; v.f = f;
  uint32_t r = v.u + 0x7FFFu + ((v.u >> 16) & 1u);   // RNE
  return (short)(r >> 16);
}

__device__ __forceinline__ float fast_tanh(float z) {
  // tanh(z) = 1 - 2/(e^{2z}+1); overflow-safe
  return 1.0f - 2.0f * __builtin_amdgcn_rcpf(__expf(2.0f * z) + 1.0f);
}

__device__ __forceinline__ void gload_lds16(const short* g, short* l) {
  __builtin_amdgcn_global_load_lds(
      (const __attribute__((address_space(1))) int*)(g),
      (__attribute__((address_space(3))) int*)(l), 16, 0, 0);
}

// Kernel 0: Wt image = bf16(W^T) in the EXACT swizzled LDS byte layout:
// element (n,k) at short index n*256 + (((k>>3) ^ (n&7))<<3) + (k&7).
__global__ void k_pack(const float* __restrict__ W, short* __restrict__ wt) {
  __shared__ float tile[64][65];
  int t = blockIdx.x, ti = t >> 2, tj = t & 3;
  int tid = threadIdx.x;
#pragma unroll
  for (int i = 0; i < 16; ++i) {
    int idx = i * 256 + tid;
    int r = idx >> 6, c = idx & 63;                 // r: k-local, c: n-local
    tile[c][r] = W[(ti * 64 + r) * 256 + tj * 64 + c];
  }
  __syncthreads();
#pragma unroll
  for (int i = 0; i < 16; ++i) {
    int idx = i * 256 + tid;
    int r = idx >> 6, c = idx & 63;                 // r: n-local, c: k-local
    int n = tj * 64 + r, k = ti * 64 + c;
    int si = n * 256 + ((((k >> 3) ^ (n & 7)) << 3) | (k & 7));
    wt[si] = f2bf(tile[r][c]);
  }
}

// Kernel 1: barrier-free streaming GEMM+tanh+dot+online-softmax+context.
// B resident in LDS (preloaded once); each wave owns 64 private rows.
__global__ __launch_bounds__(TPB)
void k_scores(const float* __restrict__ x, const short* __restrict__ wt,
              const float* __restrict__ bias, const float* __restrict__ u,
              float* __restrict__ ws_scores, float* __restrict__ ws_m,
              float* __restrict__ ws_l, float* __restrict__ ws_c) {
  __shared__ __align__(16) short lsB[D_ * D_];   // 128 KB swizzled Wt; reused as ctx at end
  __shared__ __align__(8) float bu[D_ * 2];      // (bias, u) pairs
  __shared__ float ml[16 * 2];

  const int tid  = threadIdx.x;
  const int lane = tid & 63;
  const int wv   = tid >> 6;        // 0..15
  const int cl   = lane & 15;
  const int gr   = lane >> 4;       // 0..3
  const int bid  = blockIdx.x;

  // ---- preload B (128 KB) + (bias,u) into LDS, one barrier
#pragma unroll
  for (int i = 0; i < 8; ++i) {
    int idx = i * TPB + tid;
    gload_lds16(wt + idx * 8, &lsB[idx * 8]);
  }
  if (tid < D_) {
    bu[tid * 2]     = bias[tid];
    bu[tid * 2 + 1] = u[tid];
  }
  __syncthreads();

  const size_t rowbase0 = (size_t)bid * ROWS_PER_BLOCK + wv * 64;
  const float* xw = x + (rowbase0 + cl) * D_ + gr * 8;   // A-load base for this lane

  // rolling A prefetch: chunk g = t*4+q covers rows (g>>2)*16, k-cols (g&3)*64..+63
  f4 qb[2][4];
#pragma unroll
  for (int g = 0; g < 2; ++g) {
    const float* p = xw + (g & 3) * 64;   // t=0
    qb[g][0] = *(const f4*)(p);
    qb[g][1] = *(const f4*)(p + 4);
    qb[g][2] = *(const f4*)(p + 32);
    qb[g][3] = *(const f4*)(p + 36);
  }

  float mrun = -3.4e38f, lrun = 0.f;
  f4 ctxv = (f4){0.f, 0.f, 0.f, 0.f};

  for (int t = 0; t < 4; ++t) {
    f32x4 acc[16];
#pragma unroll
    for (int nf = 0; nf < 16; ++nf) acc[nf] = (f32x4){0.f, 0.f, 0.f, 0.f};

#pragma unroll
    for (int q = 0; q < 4; ++q) {
      // consume slot q&1 -> two A-frags (kf = 2q, 2q+1)
      f4* qp = qb[q & 1];
      short8 a0, a1;
      a0[0]=f2bf(qp[0][0]); a0[1]=f2bf(qp[0][1]); a0[2]=f2bf(qp[0][2]); a0[3]=f2bf(qp[0][3]);
      a0[4]=f2bf(qp[1][0]); a0[5]=f2bf(qp[1][1]); a0[6]=f2bf(qp[1][2]); a0[7]=f2bf(qp[1][3]);
      a1[0]=f2bf(qp[2][0]); a1[1]=f2bf(qp[2][1]); a1[2]=f2bf(qp[2][2]); a1[3]=f2bf(qp[2][3]);
      a1[4]=f2bf(qp[3][0]); a1[5]=f2bf(qp[3][1]); a1[6]=f2bf(qp[3][2]); a1[7]=f2bf(qp[3][3]);
      // issue chunk g+2 into the freed slot
      int h = t * 4 + q + 2;
      if (h < 16) {
        const float* p = xw + (h >> 2) * (16 * D_) + (h & 3) * 64;
        qp[0] = *(const f4*)(p);
        qp[1] = *(const f4*)(p + 4);
        qp[2] = *(const f4*)(p + 32);
        qp[3] = *(const f4*)(p + 36);
      }
      const int kf0 = 2 * q, kf1 = 2 * q + 1;
      const int sw0 = ((kf0 * 4 + gr) ^ (cl & 7)) << 3;
      const int sw1 = ((kf1 * 4 + gr) ^ (cl & 7)) << 3;
#pragma unroll
      for (int nf = 0; nf < 16; ++nf) {
        short8 b0 = *(const short8*)&lsB[(nf * 16 + cl) * 256 + sw0];
        acc[nf] = __builtin_amdgcn_mfma_f32_16x16x32_bf16(a0, b0, acc[nf], 0, 0, 0);
        short8 b1 = *(const short8*)&lsB[(nf * 16 + cl) * 256 + sw1];
        acc[nf] = __builtin_amdgcn_mfma_f32_16x16x32_bf16(a1, b1, acc[nf], 0, 0, 0);
      }
    }

    // ---- epilogue: scores for 16 rows (row = gr*4+j), online softmax, ctx
    float sj0 = 0.f, sj1 = 0.f, sj2 = 0.f, sj3 = 0.f;
#pragma unroll
    for (int nf = 0; nf < 16; ++nf) {
      float bb = bu[(nf * 16 + cl) * 2];
      float uu = bu[(nf * 16 + cl) * 2 + 1];
      sj0 += fast_tanh(acc[nf][0] + bb) * uu;
      sj1 += fast_tanh(acc[nf][1] + bb) * uu;
      sj2 += fast_tanh(acc[nf][2] + bb) * uu;
      sj3 += fast_tanh(acc[nf][3] + bb) * uu;
    }
#pragma unroll
    for (int m = 1; m < 16; m <<= 1) {
      sj0 += __shfl_xor(sj0, m); sj1 += __shfl_xor(sj1, m);
      sj2 += __shfl_xor(sj2, m); sj3 += __shfl_xor(sj3, m);
    }
    const int rowb = bid * ROWS_PER_BLOCK + wv * 64 + t * 16;
    if (cl == 0) {
      ws_scores[rowb + gr * 4 + 0] = sj0;
      ws_scores[rowb + gr * 4 + 1] = sj1;
      ws_scores[rowb + gr * 4 + 2] = sj2;
      ws_scores[rowb + gr * 4 + 3] = sj3;
    }
    float tmax = fmaxf(fmaxf(sj0, sj1), fmaxf(sj2, sj3));
    tmax = fmaxf(tmax, __shfl_xor(tmax, 16));
    tmax = fmaxf(tmax, __shfl_xor(tmax, 32));
    float mnew = fmaxf(mrun, tmax);
    float sc = __expf(mrun - mnew);
    float e0 = __expf(sj0 - mnew), e1 = __expf(sj1 - mnew);
    float e2 = __expf(sj2 - mnew), e3 = __expf(sj3 - mnew);
    float se = e0 + e1 + e2 + e3;
    se += __shfl_xor(se, 16); se += __shfl_xor(se, 32);
    lrun = lrun * sc + se;
    mrun = mnew;
    ctxv *= sc;
    // context accumulate: re-read the (L1-hot) 16-row tile; lane owns d = lane*4..+3
    const float* xc = x + (size_t)rowb * D_ + lane * 4;
#pragma unroll
    for (int s = 0; s < 16; ++s) {
      f4 xv = *(const f4*)(xc + (size_t)s * D_);
      uint32_t eu;
      if ((s & 3) == 0)      eu = __float_as_uint(e0);
      else if ((s & 3) == 1) eu = __float_as_uint(e1);
      else if ((s & 3) == 2) eu = __float_as_uint(e2);
      else                   eu = __float_as_uint(e3);
      float es = __uint_as_float(__builtin_amdgcn_readlane(eu, (s >> 2) << 4));
      ctxv += es * xv;
    }
  }

  // ---- block combine (reuse lsB as ctx scratch)
  __syncthreads();                    // all waves done reading lsB
  ((f4*)lsB)[wv * 64 + lane] = ctxv;  // [wv][256] f32
  if (lane == 0) { ml[wv * 2] = mrun; ml[wv * 2 + 1] = lrun; }
  __syncthreads();
  if (tid < D_) {
    float M = ml[0];
#pragma unroll
    for (int w = 1; w < 16; ++w) M = fmaxf(M, ml[w * 2]);
    float L = 0.f, cd = 0.f;
#pragma unroll
    for (int w = 0; w < 16; ++w) {
      float ex = __expf(ml[w * 2] - M);
      L += ml[w * 2 + 1] * ex;
      cd += ((const float*)lsB)[w * 256 + tid] * ex;
    }
    ws_c[bid * D_ + tid] = cd;
    if (tid == 0) { ws_m[bid] = M; ws_l[bid] = L; }
  }
}

// Kernel 2: per-batch combine of 4 block partials -> context out + (M, L)
__global__ void k_combine(const float* __restrict__ ws_m, const float* __restrict__ ws_l,
                          const float* __restrict__ ws_c, float* __restrict__ out_ctx,
                          float* __restrict__ ws_M, float* __restrict__ ws_L) {
  int b = blockIdx.x, d = threadIdx.x;
  float M = -3.4e38f;
#pragma unroll
  for (int i = 0; i < BLKS_PER_BATCH; ++i) M = fmaxf(M, ws_m[b * BLKS_PER_BATCH + i]);
  float L = 0.f, c = 0.f;
#pragma unroll
  for (int i = 0; i < BLKS_PER_BATCH; ++i) {
    float f = __expf(ws_m[b * BLKS_PER_BATCH + i] - M);
    L += ws_l[b * BLKS_PER_BATCH + i] * f;
    c += ws_c[(size_t)(b * BLKS_PER_BATCH + i) * D_ + d] * f;
  }
  out_ctx[b * D_ + d] = c / L;
  if (d == 0) { ws_M[b] = M; ws_L[b] = L; }
}

// Kernel 3: weights[b,s] = exp(score - M_b) / L_b
__global__ void k_weights(const float* __restrict__ ws_scores, const float* __restrict__ ws_M,
                          const float* __restrict__ ws_L, float* __restrict__ out_w) {
  int idx = blockIdx.x * 256 + threadIdx.x;
  int b = idx >> 12;
  out_w[idx] = __expf(ws_scores[idx] - ws_M[b]) / ws_L[b];
}

extern "C" void kernel_launch(void* const* d_in, const int* in_sizes, int n_in,
                              void* d_out, int out_size, void* d_ws, size_t ws_size,
                              hipStream_t stream) {
  (void)in_sizes; (void)n_in; (void)out_size; (void)ws_size;
  const float* x    = (const float*)d_in[0];
  const float* W    = (const float*)d_in[1];
  const float* bias = (const float*)d_in[2];
  const float* u    = (const float*)d_in[3];
  float* out_ctx = (float*)d_out;                 // [64,256]
  float* out_w   = (float*)d_out + B_ * D_;       // [64,4096]

  char* ws = (char*)d_ws;
  short* wt        = (short*)(ws + 0);            // 131072 B (swizzled LDS image)
  float* ws_scores = (float*)(ws + 131072);       // 1048576 B
  float* ws_m      = (float*)(ws + 1179648);      // 1024 B (256 blocks)
  float* ws_l      = (float*)(ws + 1180672);      // 1024 B
  float* ws_c      = (float*)(ws + 1181696);      // 262144 B (256 x 256)
  float* ws_M      = (float*)(ws + 1443840);      // 256 B
  float* ws_L      = (float*)(ws + 1444096);      // 256 B

  hipLaunchKernelGGL(k_pack, dim3(16), dim3(256), 0, stream, W, wt);
  hipLaunchKernelGGL(k_scores, dim3(NBLK), dim3(TPB), 0, stream,
                     x, wt, bias, u, ws_scores, ws_m, ws_l, ws_c);
  hipLaunchKernelGGL(k_combine, dim3(B_), dim3(256), 0, stream,
                     ws_m, ws_l, ws_c, out_ctx, ws_M, ws_L);
  hipLaunchKernelGGL(k_weights, dim3(B_ * S_ / 256), dim3(256), 0, stream,
                     ws_scores, ws_M, ws_L, out_w);
}

// Round 5
// 569.615 us; speedup vs baseline: 1.5385x; 1.5385x over previous
//
#include <hip/hip_runtime.h>
#include <hip/hip_bf16.h>
#include <cstdint>
#include <cstddef>

// Problem constants
#define B_ 64
#define S_ 4096
#define D_ 256
#define TPB 512                  // 8 waves
#define NBLK 256                 // 1 block per CU; 256 blocks * 1024 rows = 262144
#define ROWS_PER_BLOCK 1024
#define ROWS_PER_WAVE 128        // 8 t-iters of 16 rows
#define BLKS_PER_BATCH 4         // 4096 rows/batch / 1024 rows/block

typedef __attribute__((ext_vector_type(8))) short short8;
typedef __attribute__((ext_vector_type(4))) float f32x4;
typedef __attribute__((ext_vector_type(4))) float f4;

__device__ __forceinline__ short f2bf(float f) {
  union { float f; uint32_t u; } v; v.f = f;
  uint32_t r = v.u + 0x7FFFu + ((v.u >> 16) & 1u);   // RNE
  return (short)(r >> 16);
}

__device__ __forceinline__ float fast_tanh(float z) {
  // tanh(z) = 1 - 2/(e^{2z}+1); overflow-safe
  return 1.0f - 2.0f * __builtin_amdgcn_rcpf(__expf(2.0f * z) + 1.0f);
}

__device__ __forceinline__ void gload_lds16(const short* g, short* l) {
  __builtin_amdgcn_global_load_lds(
      (const __attribute__((address_space(1))) int*)(g),
      (__attribute__((address_space(3))) int*)(l), 16, 0, 0);
}

// Kernel 0: Wt image = bf16(W^T) in the EXACT swizzled LDS byte layout:
// element (n,k) at short index n*256 + (((k>>3) ^ (n&7))<<3) + (k&7).
__global__ void k_pack(const float* __restrict__ W, short* __restrict__ wt) {
  __shared__ float tile[64][65];
  int t = blockIdx.x, ti = t >> 2, tj = t & 3;
  int tid = threadIdx.x;
#pragma unroll
  for (int i = 0; i < 16; ++i) {
    int idx = i * 256 + tid;
    int r = idx >> 6, c = idx & 63;                 // r: k-local, c: n-local
    tile[c][r] = W[(ti * 64 + r) * 256 + tj * 64 + c];
  }
  __syncthreads();
#pragma unroll
  for (int i = 0; i < 16; ++i) {
    int idx = i * 256 + tid;
    int r = idx >> 6, c = idx & 63;                 // r: n-local, c: k-local
    int n = tj * 64 + r, k = ti * 64 + c;
    int si = n * 256 + ((((k >> 3) ^ (n & 7)) << 3) | (k & 7));
    wt[si] = f2bf(tile[r][c]);
  }
}

// Kernel 1: barrier-free streaming GEMM+tanh+dot+online-softmax+context.
// B resident in LDS (preloaded once); each wave owns 128 private rows.
__global__ __launch_bounds__(TPB, 2)
void k_scores(const float* __restrict__ x, const short* __restrict__ wt,
              const float* __restrict__ bias, const float* __restrict__ u,
              float* __restrict__ ws_scores, float* __restrict__ ws_m,
              float* __restrict__ ws_l, float* __restrict__ ws_c) {
  __shared__ __align__(16) short lsB[D_ * D_];   // 128 KB swizzled Wt; reused as ctx at end
  __shared__ __align__(8) float bu[D_ * 2];      // (bias, u) pairs
  __shared__ float ml[8 * 2];

  const int tid  = threadIdx.x;
  const int lane = tid & 63;
  const int wv   = tid >> 6;        // 0..7
  const int cl   = lane & 15;
  const int gr   = lane >> 4;       // 0..3
  const int bid  = blockIdx.x;

  // ---- preload B (128 KB) + (bias,u) into LDS, one barrier
#pragma unroll
  for (int i = 0; i < 16; ++i) {
    int idx = i * TPB + tid;
    gload_lds16(wt + idx * 8, &lsB[idx * 8]);
  }
  if (tid < D_) {
    bu[tid * 2]     = bias[tid];
    bu[tid * 2 + 1] = u[tid];
  }
  __syncthreads();

  const size_t rowbase0 = (size_t)bid * ROWS_PER_BLOCK + wv * ROWS_PER_WAVE;
  const float* xw = x + (rowbase0 + cl) * D_ + gr * 8;   // A-load base for this lane

  // rolling A prefetch: chunk g = t*4+q covers rows (g>>2)*16, k-cols (g&3)*64..+63
  f4 qb[2][4];
#pragma unroll
  for (int g = 0; g < 2; ++g) {
    const float* p = xw + (g & 3) * 64;   // t=0
    qb[g][0] = *(const f4*)(p);
    qb[g][1] = *(const f4*)(p + 4);
    qb[g][2] = *(const f4*)(p + 32);
    qb[g][3] = *(const f4*)(p + 36);
  }

  float mrun = -3.4e38f, lrun = 0.f;
  f4 ctxv = (f4){0.f, 0.f, 0.f, 0.f};

  for (int t = 0; t < 8; ++t) {
    f32x4 acc[16];
#pragma unroll
    for (int nf = 0; nf < 16; ++nf) acc[nf] = (f32x4){0.f, 0.f, 0.f, 0.f};

#pragma unroll
    for (int q = 0; q < 4; ++q) {
      // consume slot q&1 -> two A-frags (kf = 2q, 2q+1)
      f4* qp = qb[q & 1];
      short8 a0, a1;
      a0[0]=f2bf(qp[0][0]); a0[1]=f2bf(qp[0][1]); a0[2]=f2bf(qp[0][2]); a0[3]=f2bf(qp[0][3]);
      a0[4]=f2bf(qp[1][0]); a0[5]=f2bf(qp[1][1]); a0[6]=f2bf(qp[1][2]); a0[7]=f2bf(qp[1][3]);
      a1[0]=f2bf(qp[2][0]); a1[1]=f2bf(qp[2][1]); a1[2]=f2bf(qp[2][2]); a1[3]=f2bf(qp[2][3]);
      a1[4]=f2bf(qp[3][0]); a1[5]=f2bf(qp[3][1]); a1[6]=f2bf(qp[3][2]); a1[7]=f2bf(qp[3][3]);
      // issue chunk g+2 into the freed slot (g = t*4+q)
      int h = t * 4 + q + 2;
      if (h < 32) {
        const float* p = xw + (h >> 2) * (16 * D_) + (h & 3) * 64;
        qp[0] = *(const f4*)(p);
        qp[1] = *(const f4*)(p + 4);
        qp[2] = *(const f4*)(p + 32);
        qp[3] = *(const f4*)(p + 36);
      }
      const int kf0 = 2 * q, kf1 = 2 * q + 1;
      const int sw0 = ((kf0 * 4 + gr) ^ (cl & 7)) << 3;
      const int sw1 = ((kf1 * 4 + gr) ^ (cl & 7)) << 3;
#pragma unroll
      for (int nf = 0; nf < 16; ++nf) {
        short8 b0 = *(const short8*)&lsB[(nf * 16 + cl) * 256 + sw0];
        acc[nf] = __builtin_amdgcn_mfma_f32_16x16x32_bf16(a0, b0, acc[nf], 0, 0, 0);
        short8 b1 = *(const short8*)&lsB[(nf * 16 + cl) * 256 + sw1];
        acc[nf] = __builtin_amdgcn_mfma_f32_16x16x32_bf16(a1, b1, acc[nf], 0, 0, 0);
      }
    }

    // ---- epilogue: scores for 16 rows (row = gr*4+j), online softmax, ctx
    float sj0 = 0.f, sj1 = 0.f, sj2 = 0.f, sj3 = 0.f;
#pragma unroll
    for (int nf = 0; nf < 16; ++nf) {
      float bb = bu[(nf * 16 + cl) * 2];
      float uu = bu[(nf * 16 + cl) * 2 + 1];
      sj0 += fast_tanh(acc[nf][0] + bb) * uu;
      sj1 += fast_tanh(acc[nf][1] + bb) * uu;
      sj2 += fast_tanh(acc[nf][2] + bb) * uu;
      sj3 += fast_tanh(acc[nf][3] + bb) * uu;
    }
#pragma unroll
    for (int m = 1; m < 16; m <<= 1) {
      sj0 += __shfl_xor(sj0, m); sj1 += __shfl_xor(sj1, m);
      sj2 += __shfl_xor(sj2, m); sj3 += __shfl_xor(sj3, m);
    }
    const int rowb = bid * ROWS_PER_BLOCK + wv * ROWS_PER_WAVE + t * 16;
    if (cl == 0) {
      ws_scores[rowb + gr * 4 + 0] = sj0;
      ws_scores[rowb + gr * 4 + 1] = sj1;
      ws_scores[rowb + gr * 4 + 2] = sj2;
      ws_scores[rowb + gr * 4 + 3] = sj3;
    }
    float tmax = fmaxf(fmaxf(sj0, sj1), fmaxf(sj2, sj3));
    tmax = fmaxf(tmax, __shfl_xor(tmax, 16));
    tmax = fmaxf(tmax, __shfl_xor(tmax, 32));
    float mnew = fmaxf(mrun, tmax);
    float sc = __expf(mrun - mnew);
    float e0 = __expf(sj0 - mnew), e1 = __expf(sj1 - mnew);
    float e2 = __expf(sj2 - mnew), e3 = __expf(sj3 - mnew);
    float se = e0 + e1 + e2 + e3;
    se += __shfl_xor(se, 16); se += __shfl_xor(se, 32);
    lrun = lrun * sc + se;
    mrun = mnew;
    ctxv *= sc;
    // context accumulate: re-read the (L1/L2-hot) 16-row tile; lane owns d = lane*4..+3
    const float* xc = x + (size_t)rowb * D_ + lane * 4;
#pragma unroll
    for (int s = 0; s < 16; ++s) {
      f4 xv = *(const f4*)(xc + (size_t)s * D_);
      uint32_t eu;
      if ((s & 3) == 0)      eu = __float_as_uint(e0);
      else if ((s & 3) == 1) eu = __float_as_uint(e1);
      else if ((s & 3) == 2) eu = __float_as_uint(e2);
      else                   eu = __float_as_uint(e3);
      float es = __uint_as_float(__builtin_amdgcn_readlane(eu, (s >> 2) << 4));
      ctxv += es * xv;
    }
  }

  // ---- block combine (reuse lsB as ctx scratch)
  __syncthreads();                    // all waves done reading lsB
  ((f4*)lsB)[wv * 64 + lane] = ctxv;  // [wv][256] f32
  if (lane == 0) { ml[wv * 2] = mrun; ml[wv * 2 + 1] = lrun; }
  __syncthreads();
  if (tid < D_) {
    float M = ml[0];
#pragma unroll
    for (int w = 1; w < 8; ++w) M = fmaxf(M, ml[w * 2]);
    float L = 0.f, cd = 0.f;
#pragma unroll
    for (int w = 0; w < 8; ++w) {
      float ex = __expf(ml[w * 2] - M);
      L += ml[w * 2 + 1] * ex;
      cd += ((const float*)lsB)[w * 256 + tid] * ex;
    }
    ws_c[bid * D_ + tid] = cd;
    if (tid == 0) { ws_m[bid] = M; ws_l[bid] = L; }
  }
}

// Kernel 2: per-batch combine of 4 block partials -> context out + (M, L)
__global__ void k_combine(const float* __restrict__ ws_m, const float* __restrict__ ws_l,
                          const float* __restrict__ ws_c, float* __restrict__ out_ctx,
                          float* __restrict__ ws_M, float* __restrict__ ws_L) {
  int b = blockIdx.x, d = threadIdx.x;
  float M = -3.4e38f;
#pragma unroll
  for (int i = 0; i < BLKS_PER_BATCH; ++i) M = fmaxf(M, ws_m[b * BLKS_PER_BATCH + i]);
  float L = 0.f, c = 0.f;
#pragma unroll
  for (int i = 0; i < BLKS_PER_BATCH; ++i) {
    float f = __expf(ws_m[b * BLKS_PER_BATCH + i] - M);
    L += ws_l[b * BLKS_PER_BATCH + i] * f;
    c += ws_c[(size_t)(b * BLKS_PER_BATCH + i) * D_ + d] * f;
  }
  out_ctx[b * D_ + d] = c / L;
  if (d == 0) { ws_M[b] = M; ws_L[b] = L; }
}

// Kernel 3: weights[b,s] = exp(score - M_b) / L_b
__global__ void k_weights(const float* __restrict__ ws_scores, const float* __restrict__ ws_M,
                          const float* __restrict__ ws_L, float* __restrict__ out_w) {
  int idx = blockIdx.x * 256 + threadIdx.x;
  int b = idx >> 12;
  out_w[idx] = __expf(ws_scores[idx] - ws_M[b]) / ws_L[b];
}

extern "C" void kernel_launch(void* const* d_in, const int* in_sizes, int n_in,
                              void* d_out, int out_size, void* d_ws, size_t ws_size,
                              hipStream_t stream) {
  (void)in_sizes; (void)n_in; (void)out_size; (void)ws_size;
  const float* x    = (const float*)d_in[0];
  const float* W    = (const float*)d_in[1];
  const float* bias = (const float*)d_in[2];
  const float* u    = (const float*)d_in[3];
  float* out_ctx = (float*)d_out;                 // [64,256]
  float* out_w   = (float*)d_out + B_ * D_;       // [64,4096]

  char* ws = (char*)d_ws;
  short* wt        = (short*)(ws + 0);            // 131072 B (swizzled LDS image)
  float* ws_scores = (float*)(ws + 131072);       // 1048576 B
  float* ws_m      = (float*)(ws + 1179648);      // 1024 B (256 blocks)
  float* ws_l      = (float*)(ws + 1180672);      // 1024 B
  float* ws_c      = (float*)(ws + 1181696);      // 262144 B (256 x 256)
  float* ws_M      = (float*)(ws + 1443840);      // 256 B
  float* ws_L      = (float*)(ws + 1444096);      // 256 B

  hipLaunchKernelGGL(k_pack, dim3(16), dim3(256), 0, stream, W, wt);
  hipLaunchKernelGGL(k_scores, dim3(NBLK), dim3(TPB), 0, stream,
                     x, wt, bias, u, ws_scores, ws_m, ws_l, ws_c);
  hipLaunchKernelGGL(k_combine, dim3(B_), dim3(256), 0, stream,
                     ws_m, ws_l, ws_c, out_ctx, ws_M, ws_L);
  hipLaunchKernelGGL(k_weights, dim3(B_ * S_ / 256), dim3(256), 0, stream,
                     ws_scores, ws_M, ws_L, out_w);
}